// Round 11
// baseline (430.736 us; speedup 1.0000x reference)
//
#include <hip/hip_runtime.h>
#include <math.h>

// Problem constants (B=4, N=10000 -> Nn=40000; IN=128, HID=OUT=64, H=2)
#define NN    40000
#define QSC   192   // QS table cols: Q(128) | S(64)
#define NC    448   // logical gemm cols: Q(128)|K(128)|V(128)|S(64)
#define CHN   64

#define SCAN_BLK 256
#define NBLK ((NN + SCAN_BLK - 1) / SCAN_BLK)   // 157
#define LDA 136   // LDS row pitch (bf16 elems) = 272B; 17 x 16B chunks (odd) -> conflict-free b128

typedef __attribute__((ext_vector_type(8))) short bf16x8;
typedef __attribute__((ext_vector_type(4))) float f32x4;

__device__ __forceinline__ unsigned short f2bf(float f) {   // RNE f32->bf16
  unsigned int u = __float_as_uint(f);
  unsigned int r = u + 0x7fffu + ((u >> 16) & 1u);
  return (unsigned short)(r >> 16);
}
__device__ __forceinline__ float bf2f(unsigned short h) {
  return __uint_as_float((unsigned int)h << 16);
}

// ---- edge-index dtype detection: int64 stored LE has zero odd words ----
__global__ void detect_k(const int* __restrict__ w, int* __restrict__ flag) {
  int lane = threadIdx.x & 63;
  int v = 0;
#pragma unroll
  for (int i = 0; i < 4; ++i) v |= w[2 * (lane + 64 * i) + 1];
#pragma unroll
  for (int o = 32; o; o >>= 1) v |= __shfl_xor(v, o);
  if (lane == 0 && blockIdx.x == 0) *flag = (v == 0) ? 1 : 0;
}

// ---- decode edges to int32 srcs/dsts + fused degree histogram ----
__global__ void decode_k(const int* __restrict__ w, const int* __restrict__ flag,
                         int* __restrict__ srcs, int* __restrict__ dsts,
                         int* __restrict__ deg, int E) {
  int e = blockIdx.x * blockDim.x + threadIdx.x;
  if (e >= E) return;
  int s, d;
  if (*flag) { s = w[2 * e]; d = w[2 * (E + e)]; }
  else       { s = w[e];     d = w[E + e]; }
  srcs[e] = s;
  dsts[e] = d;
  atomicAdd(&deg[d], 1);
}

// ---- pack weights: transposed bf16 hi/lo panels Bt[c][k] + f32 biases ----
__global__ void pack_all(const float* __restrict__ Wq1, const float* __restrict__ bq1,
                         const float* __restrict__ Wk1, const float* __restrict__ bk1,
                         const float* __restrict__ Wv1, const float* __restrict__ bv1,
                         const float* __restrict__ Ws1, const float* __restrict__ bs1,
                         const float* __restrict__ Wq2, const float* __restrict__ bq2,
                         const float* __restrict__ Wk2, const float* __restrict__ bk2,
                         const float* __restrict__ Wv2, const float* __restrict__ bv2,
                         const float* __restrict__ Ws2, const float* __restrict__ bs2,
                         unsigned short* __restrict__ Bh1, unsigned short* __restrict__ Bl1,
                         unsigned short* __restrict__ Bh2, unsigned short* __restrict__ Bl2,
                         float* __restrict__ bias1, float* __restrict__ bias2) {
  int i = blockIdx.x * blockDim.x + threadIdx.x;
  if (i < 57344) {                    // layer-1: c = i/128, k = i%128
    int c = i >> 7, k = i & 127;
    float v;
    if (c < 128)      v = Wq1[k * 128 + c];
    else if (c < 256) v = Wk1[k * 128 + (c - 128)];
    else if (c < 384) v = Wv1[k * 128 + (c - 256)];
    else              v = Ws1[k * 64 + (c - 384)];
    unsigned short hi = f2bf(v);
    Bh1[i] = hi;
    Bl1[i] = f2bf(v - bf2f(hi));
  } else if (i < 86016) {             // layer-2: c = j/64, k = j%64
    int j = i - 57344;
    int c = j >> 6, k = j & 63;
    float v;
    if (c < 128)      v = Wq2[k * 128 + c];
    else if (c < 256) v = Wk2[k * 128 + (c - 128)];
    else if (c < 384) v = Wv2[k * 128 + (c - 256)];
    else              v = Ws2[k * 64 + (c - 384)];
    unsigned short hi = f2bf(v);
    Bh2[j] = hi;
    Bl2[j] = f2bf(v - bf2f(hi));
  } else if (i < 86464) {             // bias1
    int c = i - 86016;
    float v;
    if (c < 128)      v = bq1[c];
    else if (c < 256) v = bk1[c - 128];
    else if (c < 384) v = bv1[c - 256];
    else              v = bs1[c - 384];
    bias1[c] = v;
  } else if (i < 86912) {             // bias2
    int c = i - 86464;
    float v;
    if (c < 128)      v = bq2[c];
    else if (c < 256) v = bk2[c - 128];
    else if (c < 384) v = bv2[c - 256];
    else              v = bs2[c - 384];
    bias2[c] = v;
  }
}

// ---- hierarchical exclusive scan of deg[NN] -> rp[NN+1], cur[NN] ----
__global__ __launch_bounds__(SCAN_BLK) void bsum_k(const int* __restrict__ deg,
                                                   int* __restrict__ bsum) {
  int t = threadIdx.x;
  int i = blockIdx.x * SCAN_BLK + t;
  int v = (i < NN) ? deg[i] : 0;
#pragma unroll
  for (int o = 32; o; o >>= 1) v += __shfl_xor(v, o);
  __shared__ int ws[4];
  if ((t & 63) == 0) ws[t >> 6] = v;
  __syncthreads();
  if (t == 0) bsum[blockIdx.x] = ws[0] + ws[1] + ws[2] + ws[3];
}

__global__ __launch_bounds__(SCAN_BLK) void bscan_k(const int* __restrict__ bsum,
                                                    int* __restrict__ boff) {
  int t = threadIdx.x;
  int lane = t & 63, w = t >> 6;
  int v = (t < NBLK) ? bsum[t] : 0;
  int incl = v;
#pragma unroll
  for (int o = 1; o < 64; o <<= 1) {
    int u = __shfl_up(incl, o);
    if (lane >= o) incl += u;
  }
  __shared__ int wsum[4];
  if (lane == 63) wsum[w] = incl;
  __syncthreads();
  int woff = 0;
  for (int j = 0; j < w; ++j) woff += wsum[j];
  if (t < NBLK) boff[t] = woff + incl - v;
}

__global__ __launch_bounds__(SCAN_BLK) void rpwrite_k(const int* __restrict__ deg,
    const int* __restrict__ boff, int* __restrict__ rp, int* __restrict__ cur) {
  int t = threadIdx.x;
  int i = blockIdx.x * SCAN_BLK + t;
  int v = (i < NN) ? deg[i] : 0;
  int lane = t & 63, w = t >> 6;
  int incl = v;
#pragma unroll
  for (int o = 1; o < 64; o <<= 1) {
    int u = __shfl_up(incl, o);
    if (lane >= o) incl += u;
  }
  __shared__ int wsum[4];
  if (lane == 63) wsum[w] = incl;
  __syncthreads();
  int woff = 0;
  for (int j = 0; j < w; ++j) woff += wsum[j];
  int ex = boff[blockIdx.x] + woff + incl - v;
  if (i < NN) { rp[i] = ex; cur[i] = ex; }
  if (i == NN - 1) rp[NN] = ex + v;   // == E
}

__global__ void scatter_k(const int* __restrict__ srcs, const int* __restrict__ dsts,
                          int* __restrict__ cur, int* __restrict__ col, int E) {
  int e = blockIdx.x * blockDim.x + threadIdx.x;
  if (e < E) {
    int p = atomicAdd(&cur[dsts[e]], 1);
    col[p] = srcs[e];
  }
}

// ---- MFMA GEMM, 3-pass split-bf16 (~f32-exact), routed epilogue ----
// C[M][448] = A[M][K] @ W[K][448] + bias. BM=BN=64, 4 waves: wave w owns rows
// 16w..16w+15, 4 n-subtiles. A staged hi/lo in LDS (whole K); B-frags read
// directly from L2-resident transposed panels Bt[c][k] (16B/lane contiguous).
__global__ __launch_bounds__(256) void gemm_mfma(const float* __restrict__ A,
    const unsigned short* __restrict__ Bh, const unsigned short* __restrict__ Bl,
    const float* __restrict__ bias,
    float* __restrict__ QS, unsigned short* __restrict__ KVH, int K) {
  __shared__ unsigned short Ah[64 * LDA];
  __shared__ unsigned short Al[64 * LDA];
  int bm = blockIdx.y << 6, bn = blockIdx.x << 6;
  int tid = threadIdx.x;
  // stage A rows hi/lo in LDS
  {
    int per = K >> 2;                    // 32 (K=128) or 16 (K=64)
    int row = tid >> 2, c0 = (tid & 3) * per;
    const float* ga = A + (size_t)(bm + row) * K + c0;
    unsigned short* ah = Ah + row * LDA + c0;
    unsigned short* al = Al + row * LDA + c0;
    for (int j = 0; j < per; j += 4) {
      float4 v = *(const float4*)(ga + j);
      ushort4 h, l;
      h.x = f2bf(v.x); h.y = f2bf(v.y); h.z = f2bf(v.z); h.w = f2bf(v.w);
      l.x = f2bf(v.x - bf2f(h.x)); l.y = f2bf(v.y - bf2f(h.y));
      l.z = f2bf(v.z - bf2f(h.z)); l.w = f2bf(v.w - bf2f(h.w));
      *(ushort4*)(ah + j) = h;
      *(ushort4*)(al + j) = l;
    }
  }
  __syncthreads();
  // compute: mfma_f32_16x16x32_bf16; A-frag lane l: row=l&15, k=(l>>4)*8+j
  int w = tid >> 6, l = tid & 63;
  int lr = l & 15, lk = (l >> 4) << 3;
  f32x4 z = {0.f, 0.f, 0.f, 0.f};
  f32x4 acc[4] = {z, z, z, z};
  int arow = (16 * w + lr) * LDA;
  int ksteps = K >> 5;
  for (int ks = 0; ks < ksteps; ++ks) {
    int ko = (ks << 5) + lk;
    bf16x8 a_h = *(const bf16x8*)&Ah[arow + ko];
    bf16x8 a_l = *(const bf16x8*)&Al[arow + ko];
#pragma unroll
    for (int ns = 0; ns < 4; ++ns) {
      size_t boff = (size_t)(bn + 16 * ns + lr) * K + ko;
      bf16x8 b_h = *(const bf16x8*)(Bh + boff);
      bf16x8 b_l = *(const bf16x8*)(Bl + boff);
      acc[ns] = __builtin_amdgcn_mfma_f32_16x16x32_bf16(a_h, b_h, acc[ns], 0, 0, 0);
      acc[ns] = __builtin_amdgcn_mfma_f32_16x16x32_bf16(a_l, b_h, acc[ns], 0, 0, 0);
      acc[ns] = __builtin_amdgcn_mfma_f32_16x16x32_bf16(a_h, b_l, acc[ns], 0, 0, 0);
    }
  }
  // epilogue: C/D lane l: col=l&15 (+16ns), row=(l>>4)*4+reg (+16w)
  int rowb = bm + 16 * w + ((l >> 4) << 2);
#pragma unroll
  for (int ns = 0; ns < 4; ++ns) {
    int c = bn + (ns << 4) + lr;
    float bb = bias[c];
#pragma unroll
    for (int r = 0; r < 4; ++r) {
      float o = acc[ns][r] + bb;
      int row = rowb + r;
      if (c < 128) {
        QS[(size_t)row * QSC + c] = o;
      } else if (c < 384) {
        int isV = (c >= 256) ? 1 : 0;
        int kc = c - 128 - (isV << 7);
        int hh = kc >> 6, ch = kc & 63;
        KVH[(size_t)row * 256 + hh * 128 + (ch >> 2) * 8 + (isV << 2) + (ch & 3)] = f2bf(o);
      } else {
        QS[(size_t)row * QSC + 128 + (c - 384)] = o;
      }
    }
  }
}

// ---- fused edge-softmax aggregation + head-mean + skip (+ leaky relu) ----
__global__ __launch_bounds__(128) void agg_fused(const float* __restrict__ QS,
    const unsigned short* __restrict__ KVH,
    const int* __restrict__ rp, const int* __restrict__ col,
    float* __restrict__ out, int act) {
  int dst = blockIdx.x;
  int h = threadIdx.x >> 6;    // 0 or 1
  int lane = threadIdx.x & 63;
  int g = lane >> 4;           // group 0..3
  int sl = lane & 15;          // sublane: channels 4*sl .. 4*sl+3
  const float scale = 0.125f;  // 1/sqrt(64)

  float4 q4 = *(const float4*)(QS + (size_t)dst * QSC + h * 64 + 4 * sl);
  q4.x *= scale; q4.y *= scale; q4.z *= scale; q4.w *= scale;
  const unsigned short* __restrict__ kvb = KVH + h * 128 + sl * 8;

  float m = -INFINITY, d = 0.f;
  float4 acc = {0.f, 0.f, 0.f, 0.f};
  int e0 = rp[dst], e1 = rp[dst + 1];

  int e = e0 + g;
  if (e < e1) {
    int sCur = col[e];
    int en = e + 4;
    int sNxt = (en < e1) ? col[en] : sCur;
    uint4 uC = *(const uint4*)(kvb + (size_t)sCur * 256);
    while (true) {
      uint4 uN = *(const uint4*)(kvb + (size_t)sNxt * 256);
      int enn = e + 8;
      int sNN = (enn < e1) ? col[enn] : sNxt;
      float k0 = __uint_as_float(uC.x << 16);
      float k1 = __uint_as_float(uC.x & 0xffff0000u);
      float k2 = __uint_as_float(uC.y << 16);
      float k3 = __uint_as_float(uC.y & 0xffff0000u);
      float p = q4.x * k0 + q4.y * k1 + q4.z * k2 + q4.w * k3;
      p += __shfl_xor(p, 1); p += __shfl_xor(p, 2);
      p += __shfl_xor(p, 4); p += __shfl_xor(p, 8);
      float mn = fmaxf(m, p);
      float corr = __expf(m - mn);   // first edge: exp(-inf)=0
      float wgt = __expf(p - mn);
      float v0 = __uint_as_float(uC.z << 16);
      float v1 = __uint_as_float(uC.z & 0xffff0000u);
      float v2 = __uint_as_float(uC.w << 16);
      float v3 = __uint_as_float(uC.w & 0xffff0000u);
      d = d * corr + wgt;
      acc.x = acc.x * corr + wgt * v0;
      acc.y = acc.y * corr + wgt * v1;
      acc.z = acc.z * corr + wgt * v2;
      acc.w = acc.w * corr + wgt * v3;
      m = mn;
      e += 4;
      if (e >= e1) break;
      uC = uN; sNxt = sNN;
    }
  }

#pragma unroll
  for (int o = 16; o <= 32; o <<= 1) {
    float m2 = __shfl_xor(m, o);
    float d2 = __shfl_xor(d, o);
    float ax = __shfl_xor(acc.x, o), ay = __shfl_xor(acc.y, o);
    float az = __shfl_xor(acc.z, o), aw = __shfl_xor(acc.w, o);
    float mn = fmaxf(m, m2);
    float c1 = __expf(fmaxf(m - mn, -88.f));   // NaN-guard for empty groups
    float c2 = __expf(fmaxf(m2 - mn, -88.f));
    d = d * c1 + d2 * c2;
    acc.x = acc.x * c1 + ax * c2;
    acc.y = acc.y * c1 + ay * c2;
    acc.z = acc.z * c1 + az * c2;
    acc.w = acc.w * c1 + aw * c2;
    m = mn;
  }
  float inv = 1.0f / fmaxf(d, 1e-16f);
  float4 r = {acc.x * inv, acc.y * inv, acc.z * inv, acc.w * inv};

  __shared__ float s1[64];
  if (h == 1 && g == 0) *(float4*)&s1[4 * sl] = r;
  __syncthreads();
  if (h == 0 && g == 0) {
    const float4 rr = *(const float4*)&s1[4 * sl];
    const float4 sk = *(const float4*)(QS + (size_t)dst * QSC + 128 + 4 * sl);
    float4 o;
    o.x = 0.5f * (r.x + rr.x) + sk.x;
    o.y = 0.5f * (r.y + rr.y) + sk.y;
    o.z = 0.5f * (r.z + rr.z) + sk.z;
    o.w = 0.5f * (r.w + rr.w) + sk.w;
    if (act) {
      o.x = o.x > 0.f ? o.x : 0.1f * o.x;
      o.y = o.y > 0.f ? o.y : 0.1f * o.y;
      o.z = o.z > 0.f ? o.z : 0.1f * o.z;
      o.w = o.w > 0.f ? o.w : 0.1f * o.w;
    }
    *(float4*)(out + (size_t)dst * CHN + 4 * sl) = o;
  }
}

extern "C" void kernel_launch(void* const* d_in, const int* in_sizes, int n_in,
                              void* d_out, int out_size, void* d_ws, size_t ws_size,
                              hipStream_t stream) {
  const float* x = (const float*)d_in[0];
  const int* ei_raw = (const int*)d_in[1];   // int32 OR int64 (runtime-detected)
  const float *Wq1 = (const float*)d_in[2],  *bq1 = (const float*)d_in[3],
              *Wk1 = (const float*)d_in[4],  *bk1 = (const float*)d_in[5],
              *Wv1 = (const float*)d_in[6],  *bv1 = (const float*)d_in[7],
              *Ws1 = (const float*)d_in[8],  *bs1 = (const float*)d_in[9],
              *Wq2 = (const float*)d_in[10], *bq2 = (const float*)d_in[11],
              *Wk2 = (const float*)d_in[12], *bk2 = (const float*)d_in[13],
              *Wv2 = (const float*)d_in[14], *bv2 = (const float*)d_in[15],
              *Ws2 = (const float*)d_in[16], *bs2 = (const float*)d_in[17];
  float* out = (float*)d_out;
  const int E = in_sizes[1] / 2;

  char* base = (char*)d_ws;
  size_t off = 0;
  auto take = [&](size_t bytes) {
    char* p = base + off;
    off += (bytes + 255) & ~(size_t)255;
    return p;
  };
  unsigned short* Bh1 = (unsigned short*)take((size_t)57344 * 2);
  unsigned short* Bl1 = (unsigned short*)take((size_t)57344 * 2);
  unsigned short* Bh2 = (unsigned short*)take((size_t)28672 * 2);
  unsigned short* Bl2 = (unsigned short*)take((size_t)28672 * 2);
  float* bias1 = (float*)take(NC * 4);
  float* bias2 = (float*)take(NC * 4);
  int*   flag  = (int*)take(256);
  int*   deg   = (int*)take((size_t)NN * 4);
  int*   rp    = (int*)take((size_t)(NN + 1) * 4);
  int*   cur   = (int*)take((size_t)(NN + 1) * 4);
  int*   bsum  = (int*)take((size_t)NBLK * 4);
  int*   boff  = (int*)take((size_t)NBLK * 4);
  int*   srcs  = (int*)take((size_t)E * 4);
  int*   dsts  = (int*)take((size_t)E * 4);
  int*   col   = (int*)take((size_t)E * 4);
  float* QS    = (float*)take((size_t)NN * QSC * 4);                  // 30.7 MB
  unsigned short* KVH = (unsigned short*)take((size_t)NN * 256 * 2);  // 20.5 MB
  float* Hbuf  = (float*)take((size_t)NN * CHN * 4);
  (void)ws_size; (void)n_in; (void)out_size;

  // weight packing + edge decode + CSR build (same edge list for both layers)
  hipMemsetAsync(deg, 0, (size_t)NN * 4, stream);
  pack_all<<<(86912 + 255) / 256, 256, 0, stream>>>(
      Wq1, bq1, Wk1, bk1, Wv1, bv1, Ws1, bs1,
      Wq2, bq2, Wk2, bk2, Wv2, bv2, Ws2, bs2,
      Bh1, Bl1, Bh2, Bl2, bias1, bias2);
  detect_k<<<1, 64, 0, stream>>>(ei_raw, flag);
  decode_k<<<(E + 255) / 256, 256, 0, stream>>>(ei_raw, flag, srcs, dsts, deg, E);
  bsum_k<<<NBLK, SCAN_BLK, 0, stream>>>(deg, bsum);
  bscan_k<<<1, SCAN_BLK, 0, stream>>>(bsum, boff);
  rpwrite_k<<<NBLK, SCAN_BLK, 0, stream>>>(deg, boff, rp, cur);
  scatter_k<<<(E + 255) / 256, 256, 0, stream>>>(srcs, dsts, cur, col, E);

  // layer 1: x[40000x128] -> QS/KVH -> fused agg -> Hbuf (leaky relu)
  gemm_mfma<<<dim3(7, NN / 64), 256, 0, stream>>>(x, Bh1, Bl1, bias1, QS, KVH, 128);
  agg_fused<<<NN, 128, 0, stream>>>(QS, KVH, rp, col, Hbuf, 1);

  // layer 2: Hbuf[40000x64] -> QS/KVH -> fused agg -> out (no activation)
  gemm_mfma<<<dim3(7, NN / 64), 256, 0, stream>>>(Hbuf, Bh2, Bl2, bias2, QS, KVH, 64);
  agg_fused<<<NN, 128, 0, stream>>>(QS, KVH, rp, col, out, 0);
}

// Round 12
// 430.185 us; speedup vs baseline: 1.0013x; 1.0013x over previous
//
#include <hip/hip_runtime.h>
#include <math.h>

// Problem constants (B=4, N=10000 -> Nn=40000; IN=128, HID=OUT=64, H=2)
#define NN    40000
#define QSC   192   // QS table cols: Q(128) | S(64)
#define NC    448   // logical gemm cols: Q(128)|K(128)|V(128)|S(64)
#define CHN   64

#define SCAN_BLK 256
#define NBLK ((NN + SCAN_BLK - 1) / SCAN_BLK)   // 157
#define LDA 136   // LDS A pitch (bf16 elems) = 272B (16B-aligned rows)

typedef __attribute__((ext_vector_type(8))) short bf16x8;
typedef __attribute__((ext_vector_type(4))) float f32x4;

__device__ __forceinline__ unsigned short f2bf(float f) {   // RNE f32->bf16
  unsigned int u = __float_as_uint(f);
  unsigned int r = u + 0x7fffu + ((u >> 16) & 1u);
  return (unsigned short)(r >> 16);
}
__device__ __forceinline__ float bf2f(unsigned short h) {
  return __uint_as_float((unsigned int)h << 16);
}

// ---- edge-index dtype detection: int64 stored LE has zero odd words ----
__global__ void detect_k(const int* __restrict__ w, int* __restrict__ flag) {
  int lane = threadIdx.x & 63;
  int v = 0;
#pragma unroll
  for (int i = 0; i < 4; ++i) v |= w[2 * (lane + 64 * i) + 1];
#pragma unroll
  for (int o = 32; o; o >>= 1) v |= __shfl_xor(v, o);
  if (lane == 0 && blockIdx.x == 0) *flag = (v == 0) ? 1 : 0;
}

// ---- decode edges to int32 srcs/dsts + fused degree histogram ----
__global__ void decode_k(const int* __restrict__ w, const int* __restrict__ flag,
                         int* __restrict__ srcs, int* __restrict__ dsts,
                         int* __restrict__ deg, int E) {
  int e = blockIdx.x * blockDim.x + threadIdx.x;
  if (e >= E) return;
  int s, d;
  if (*flag) { s = w[2 * e]; d = w[2 * (E + e)]; }
  else       { s = w[e];     d = w[E + e]; }
  srcs[e] = s;
  dsts[e] = d;
  atomicAdd(&deg[d], 1);
}

// ---- pack weights: transposed bf16 hi/lo panels Bt[c][k] + f32 biases ----
__global__ void pack_all(const float* __restrict__ Wq1, const float* __restrict__ bq1,
                         const float* __restrict__ Wk1, const float* __restrict__ bk1,
                         const float* __restrict__ Wv1, const float* __restrict__ bv1,
                         const float* __restrict__ Ws1, const float* __restrict__ bs1,
                         const float* __restrict__ Wq2, const float* __restrict__ bq2,
                         const float* __restrict__ Wk2, const float* __restrict__ bk2,
                         const float* __restrict__ Wv2, const float* __restrict__ bv2,
                         const float* __restrict__ Ws2, const float* __restrict__ bs2,
                         unsigned short* __restrict__ Bh1, unsigned short* __restrict__ Bl1,
                         unsigned short* __restrict__ Bh2, unsigned short* __restrict__ Bl2,
                         float* __restrict__ bias1, float* __restrict__ bias2) {
  int i = blockIdx.x * blockDim.x + threadIdx.x;
  if (i < 57344) {                    // layer-1: c = i/128, k = i%128
    int c = i >> 7, k = i & 127;
    float v;
    if (c < 128)      v = Wq1[k * 128 + c];
    else if (c < 256) v = Wk1[k * 128 + (c - 128)];
    else if (c < 384) v = Wv1[k * 128 + (c - 256)];
    else              v = Ws1[k * 64 + (c - 384)];
    unsigned short hi = f2bf(v);
    Bh1[i] = hi;
    Bl1[i] = f2bf(v - bf2f(hi));
  } else if (i < 86016) {             // layer-2: c = j/64, k = j%64
    int j = i - 57344;
    int c = j >> 6, k = j & 63;
    float v;
    if (c < 128)      v = Wq2[k * 128 + c];
    else if (c < 256) v = Wk2[k * 128 + (c - 128)];
    else if (c < 384) v = Wv2[k * 128 + (c - 256)];
    else              v = Ws2[k * 64 + (c - 384)];
    unsigned short hi = f2bf(v);
    Bh2[j] = hi;
    Bl2[j] = f2bf(v - bf2f(hi));
  } else if (i < 86464) {             // bias1
    int c = i - 86016;
    float v;
    if (c < 128)      v = bq1[c];
    else if (c < 256) v = bk1[c - 128];
    else if (c < 384) v = bv1[c - 256];
    else              v = bs1[c - 384];
    bias1[c] = v;
  } else if (i < 86912) {             // bias2
    int c = i - 86464;
    float v;
    if (c < 128)      v = bq2[c];
    else if (c < 256) v = bk2[c - 128];
    else if (c < 384) v = bv2[c - 256];
    else              v = bs2[c - 384];
    bias2[c] = v;
  }
}

// ---- hierarchical exclusive scan of deg[NN] -> rp[NN+1], cur[NN] ----
__global__ __launch_bounds__(SCAN_BLK) void bsum_k(const int* __restrict__ deg,
                                                   int* __restrict__ bsum) {
  int t = threadIdx.x;
  int i = blockIdx.x * SCAN_BLK + t;
  int v = (i < NN) ? deg[i] : 0;
#pragma unroll
  for (int o = 32; o; o >>= 1) v += __shfl_xor(v, o);
  __shared__ int ws[4];
  if ((t & 63) == 0) ws[t >> 6] = v;
  __syncthreads();
  if (t == 0) bsum[blockIdx.x] = ws[0] + ws[1] + ws[2] + ws[3];
}

__global__ __launch_bounds__(SCAN_BLK) void bscan_k(const int* __restrict__ bsum,
                                                    int* __restrict__ boff) {
  int t = threadIdx.x;
  int lane = t & 63, w = t >> 6;
  int v = (t < NBLK) ? bsum[t] : 0;
  int incl = v;
#pragma unroll
  for (int o = 1; o < 64; o <<= 1) {
    int u = __shfl_up(incl, o);
    if (lane >= o) incl += u;
  }
  __shared__ int wsum[4];
  if (lane == 63) wsum[w] = incl;
  __syncthreads();
  int woff = 0;
  for (int j = 0; j < w; ++j) woff += wsum[j];
  if (t < NBLK) boff[t] = woff + incl - v;
}

__global__ __launch_bounds__(SCAN_BLK) void rpwrite_k(const int* __restrict__ deg,
    const int* __restrict__ boff, int* __restrict__ rp, int* __restrict__ cur) {
  int t = threadIdx.x;
  int i = blockIdx.x * SCAN_BLK + t;
  int v = (i < NN) ? deg[i] : 0;
  int lane = t & 63, w = t >> 6;
  int incl = v;
#pragma unroll
  for (int o = 1; o < 64; o <<= 1) {
    int u = __shfl_up(incl, o);
    if (lane >= o) incl += u;
  }
  __shared__ int wsum[4];
  if (lane == 63) wsum[w] = incl;
  __syncthreads();
  int woff = 0;
  for (int j = 0; j < w; ++j) woff += wsum[j];
  int ex = boff[blockIdx.x] + woff + incl - v;
  if (i < NN) { rp[i] = ex; cur[i] = ex; }
  if (i == NN - 1) rp[NN] = ex + v;   // == E
}

__global__ void scatter_k(const int* __restrict__ srcs, const int* __restrict__ dsts,
                          int* __restrict__ cur, int* __restrict__ col, int E) {
  int e = blockIdx.x * blockDim.x + threadIdx.x;
  if (e < E) {
    int p = atomicAdd(&cur[dsts[e]], 1);
    col[p] = srcs[e];
  }
}

// ---- MFMA GEMM, 3-pass split-bf16 (~f32-exact), LDS-transposed epilogue ----
// C[M][448] = A[M][K] @ W[K][448] + bias. BM=BN=64; 4 waves, wave w owns rows
// 16w..16w+15 x 4 n-subtiles. Template K -> fully unrolled k-loop (pipelined
// B loads). Epilogue stages the 64x64 f32 C-tile in LDS (aliases Ah), then
// each thread writes ONE ROW x 16 contiguous cols: float4 to QS / ushort4 to
// KVH (fixes the round-11 2-byte scatter RMW that made both layers 123us).
template<int K>
__global__ __launch_bounds__(256) void gemm_mfma(const float* __restrict__ A,
    const unsigned short* __restrict__ Bh, const unsigned short* __restrict__ Bl,
    const float* __restrict__ bias,
    float* __restrict__ QS, unsigned short* __restrict__ KVH) {
  __shared__ unsigned short Ah[64 * LDA];   // 17408 B (also aliased as C-tile)
  __shared__ unsigned short Al[64 * LDA];
  int bm = blockIdx.y << 6, bn = blockIdx.x << 6;
  int tid = threadIdx.x;
  // stage A rows hi/lo in LDS
  {
    constexpr int per = K >> 2;            // 32 (K=128) or 16 (K=64)
    int row = tid >> 2, c0 = (tid & 3) * per;
    const float* ga = A + (size_t)(bm + row) * K + c0;
    unsigned short* ah = Ah + row * LDA + c0;
    unsigned short* al = Al + row * LDA + c0;
#pragma unroll
    for (int j = 0; j < per; j += 4) {
      float4 v = *(const float4*)(ga + j);
      ushort4 h, l;
      h.x = f2bf(v.x); h.y = f2bf(v.y); h.z = f2bf(v.z); h.w = f2bf(v.w);
      l.x = f2bf(v.x - bf2f(h.x)); l.y = f2bf(v.y - bf2f(h.y));
      l.z = f2bf(v.z - bf2f(h.z)); l.w = f2bf(v.w - bf2f(h.w));
      *(ushort4*)(ah + j) = h;
      *(ushort4*)(al + j) = l;
    }
  }
  __syncthreads();
  // compute: mfma_f32_16x16x32_bf16; A-frag lane l: row=l&15, k=(l>>4)*8+j
  int w = tid >> 6, l = tid & 63;
  int lr = l & 15, lk = (l >> 4) << 3;
  f32x4 z = {0.f, 0.f, 0.f, 0.f};
  f32x4 acc[4] = {z, z, z, z};
  int arow = (16 * w + lr) * LDA;
#pragma unroll
  for (int ks = 0; ks < (K >> 5); ++ks) {
    int ko = (ks << 5) + lk;
    bf16x8 a_h = *(const bf16x8*)&Ah[arow + ko];
    bf16x8 a_l = *(const bf16x8*)&Al[arow + ko];
#pragma unroll
    for (int ns = 0; ns < 4; ++ns) {
      size_t boff = (size_t)(bn + 16 * ns + lr) * K + ko;
      bf16x8 b_h = *(const bf16x8*)(Bh + boff);
      bf16x8 b_l = *(const bf16x8*)(Bl + boff);
      acc[ns] = __builtin_amdgcn_mfma_f32_16x16x32_bf16(a_h, b_h, acc[ns], 0, 0, 0);
      acc[ns] = __builtin_amdgcn_mfma_f32_16x16x32_bf16(a_l, b_h, acc[ns], 0, 0, 0);
      acc[ns] = __builtin_amdgcn_mfma_f32_16x16x32_bf16(a_h, b_l, acc[ns], 0, 0, 0);
    }
  }
  // ---- epilogue phase 1: stage C-tile (64x64 f32, pitch 68) in LDS ----
  float* Cs = reinterpret_cast<float*>(Ah);   // 64*68*4 = 17408 B, fits Ah
  __syncthreads();                            // all A reads done before alias
  {
    int rowb = 16 * w + ((l >> 4) << 2);      // tile-local row base
#pragma unroll
    for (int ns = 0; ns < 4; ++ns) {
      int c = (ns << 4) + lr;                 // tile-local col
#pragma unroll
      for (int r = 0; r < 4; ++r)
        Cs[(rowb + r) * 68 + c] = acc[ns][r];
    }
  }
  __syncthreads();
  // ---- epilogue phase 2: row-contiguous routed writeout ----
  {
    int row = tid >> 2;                       // 0..63
    int sg = (tid & 3) << 4;                  // col seg 0/16/32/48
    int grow = bm + row;
    int c0 = bn + sg;
    float v[16];
#pragma unroll
    for (int q = 0; q < 4; ++q) {
      float4 t = *(float4*)&Cs[row * 68 + sg + 4 * q];
      float4 bb = *(const float4*)&bias[c0 + 4 * q];
      v[4 * q + 0] = t.x + bb.x; v[4 * q + 1] = t.y + bb.y;
      v[4 * q + 2] = t.z + bb.z; v[4 * q + 3] = t.w + bb.w;
    }
    if (c0 < 128) {                           // Q -> f32
      float* qp = QS + (size_t)grow * QSC + c0;
#pragma unroll
      for (int q = 0; q < 4; ++q)
        *(float4*)(qp + 4 * q) = make_float4(v[4*q], v[4*q+1], v[4*q+2], v[4*q+3]);
    } else if (c0 < 384) {                    // K/V -> bf16 interleaved
      int isV = (c0 >= 256) ? 1 : 0;
      int ch0 = c0 - 128 - (isV << 7);        // 0..112 (mult of 16)
      int hh = ch0 >> 6, chh = ch0 & 63;
      size_t base = (size_t)grow * 256 + hh * 128 + (chh >> 2) * 8 + (isV << 2);
#pragma unroll
      for (int t = 0; t < 4; ++t) {
        ushort4 w4;
        w4.x = f2bf(v[4*t]); w4.y = f2bf(v[4*t+1]);
        w4.z = f2bf(v[4*t+2]); w4.w = f2bf(v[4*t+3]);
        *(ushort4*)(KVH + base + t * 8) = w4;
      }
    } else {                                  // S -> f32
      float* sp = QS + (size_t)grow * QSC + 128 + (c0 - 384);
#pragma unroll
      for (int q = 0; q < 4; ++q)
        *(float4*)(sp + 4 * q) = make_float4(v[4*q], v[4*q+1], v[4*q+2], v[4*q+3]);
    }
  }
}

// ---- fused edge-softmax aggregation + head-mean + skip (+ leaky relu) ----
__global__ __launch_bounds__(128) void agg_fused(const float* __restrict__ QS,
    const unsigned short* __restrict__ KVH,
    const int* __restrict__ rp, const int* __restrict__ col,
    float* __restrict__ out, int act) {
  int dst = blockIdx.x;
  int h = threadIdx.x >> 6;    // 0 or 1
  int lane = threadIdx.x & 63;
  int g = lane >> 4;           // group 0..3
  int sl = lane & 15;          // sublane: channels 4*sl .. 4*sl+3
  const float scale = 0.125f;  // 1/sqrt(64)

  float4 q4 = *(const float4*)(QS + (size_t)dst * QSC + h * 64 + 4 * sl);
  q4.x *= scale; q4.y *= scale; q4.z *= scale; q4.w *= scale;
  const unsigned short* __restrict__ kvb = KVH + h * 128 + sl * 8;

  float m = -INFINITY, d = 0.f;
  float4 acc = {0.f, 0.f, 0.f, 0.f};
  int e0 = rp[dst], e1 = rp[dst + 1];

  int e = e0 + g;
  if (e < e1) {
    int sCur = col[e];
    int en = e + 4;
    int sNxt = (en < e1) ? col[en] : sCur;
    uint4 uC = *(const uint4*)(kvb + (size_t)sCur * 256);
    while (true) {
      uint4 uN = *(const uint4*)(kvb + (size_t)sNxt * 256);
      int enn = e + 8;
      int sNN = (enn < e1) ? col[enn] : sNxt;
      float k0 = __uint_as_float(uC.x << 16);
      float k1 = __uint_as_float(uC.x & 0xffff0000u);
      float k2 = __uint_as_float(uC.y << 16);
      float k3 = __uint_as_float(uC.y & 0xffff0000u);
      float p = q4.x * k0 + q4.y * k1 + q4.z * k2 + q4.w * k3;
      p += __shfl_xor(p, 1); p += __shfl_xor(p, 2);
      p += __shfl_xor(p, 4); p += __shfl_xor(p, 8);
      float mn = fmaxf(m, p);
      float corr = __expf(m - mn);   // first edge: exp(-inf)=0
      float wgt = __expf(p - mn);
      float v0 = __uint_as_float(uC.z << 16);
      float v1 = __uint_as_float(uC.z & 0xffff0000u);
      float v2 = __uint_as_float(uC.w << 16);
      float v3 = __uint_as_float(uC.w & 0xffff0000u);
      d = d * corr + wgt;
      acc.x = acc.x * corr + wgt * v0;
      acc.y = acc.y * corr + wgt * v1;
      acc.z = acc.z * corr + wgt * v2;
      acc.w = acc.w * corr + wgt * v3;
      m = mn;
      e += 4;
      if (e >= e1) break;
      uC = uN; sNxt = sNN;
    }
  }

#pragma unroll
  for (int o = 16; o <= 32; o <<= 1) {
    float m2 = __shfl_xor(m, o);
    float d2 = __shfl_xor(d, o);
    float ax = __shfl_xor(acc.x, o), ay = __shfl_xor(acc.y, o);
    float az = __shfl_xor(acc.z, o), aw = __shfl_xor(acc.w, o);
    float mn = fmaxf(m, m2);
    float c1 = __expf(fmaxf(m - mn, -88.f));   // NaN-guard for empty groups
    float c2 = __expf(fmaxf(m2 - mn, -88.f));
    d = d * c1 + d2 * c2;
    acc.x = acc.x * c1 + ax * c2;
    acc.y = acc.y * c1 + ay * c2;
    acc.z = acc.z * c1 + az * c2;
    acc.w = acc.w * c1 + aw * c2;
    m = mn;
  }
  float inv = 1.0f / fmaxf(d, 1e-16f);
  float4 r = {acc.x * inv, acc.y * inv, acc.z * inv, acc.w * inv};

  __shared__ float s1[64];
  if (h == 1 && g == 0) *(float4*)&s1[4 * sl] = r;
  __syncthreads();
  if (h == 0 && g == 0) {
    const float4 rr = *(const float4*)&s1[4 * sl];
    const float4 sk = *(const float4*)(QS + (size_t)dst * QSC + 128 + 4 * sl);
    float4 o;
    o.x = 0.5f * (r.x + rr.x) + sk.x;
    o.y = 0.5f * (r.y + rr.y) + sk.y;
    o.z = 0.5f * (r.z + rr.z) + sk.z;
    o.w = 0.5f * (r.w + rr.w) + sk.w;
    if (act) {
      o.x = o.x > 0.f ? o.x : 0.1f * o.x;
      o.y = o.y > 0.f ? o.y : 0.1f * o.y;
      o.z = o.z > 0.f ? o.z : 0.1f * o.z;
      o.w = o.w > 0.f ? o.w : 0.1f * o.w;
    }
    *(float4*)(out + (size_t)dst * CHN + 4 * sl) = o;
  }
}

extern "C" void kernel_launch(void* const* d_in, const int* in_sizes, int n_in,
                              void* d_out, int out_size, void* d_ws, size_t ws_size,
                              hipStream_t stream) {
  const float* x = (const float*)d_in[0];
  const int* ei_raw = (const int*)d_in[1];   // int32 OR int64 (runtime-detected)
  const float *Wq1 = (const float*)d_in[2],  *bq1 = (const float*)d_in[3],
              *Wk1 = (const float*)d_in[4],  *bk1 = (const float*)d_in[5],
              *Wv1 = (const float*)d_in[6],  *bv1 = (const float*)d_in[7],
              *Ws1 = (const float*)d_in[8],  *bs1 = (const float*)d_in[9],
              *Wq2 = (const float*)d_in[10], *bq2 = (const float*)d_in[11],
              *Wk2 = (const float*)d_in[12], *bk2 = (const float*)d_in[13],
              *Wv2 = (const float*)d_in[14], *bv2 = (const float*)d_in[15],
              *Ws2 = (const float*)d_in[16], *bs2 = (const float*)d_in[17];
  float* out = (float*)d_out;
  const int E = in_sizes[1] / 2;

  char* base = (char*)d_ws;
  size_t off = 0;
  auto take = [&](size_t bytes) {
    char* p = base + off;
    off += (bytes + 255) & ~(size_t)255;
    return p;
  };
  unsigned short* Bh1 = (unsigned short*)take((size_t)57344 * 2);
  unsigned short* Bl1 = (unsigned short*)take((size_t)57344 * 2);
  unsigned short* Bh2 = (unsigned short*)take((size_t)28672 * 2);
  unsigned short* Bl2 = (unsigned short*)take((size_t)28672 * 2);
  float* bias1 = (float*)take(NC * 4);
  float* bias2 = (float*)take(NC * 4);
  int*   flag  = (int*)take(256);
  int*   deg   = (int*)take((size_t)NN * 4);
  int*   rp    = (int*)take((size_t)(NN + 1) * 4);
  int*   cur   = (int*)take((size_t)(NN + 1) * 4);
  int*   bsum  = (int*)take((size_t)NBLK * 4);
  int*   boff  = (int*)take((size_t)NBLK * 4);
  int*   srcs  = (int*)take((size_t)E * 4);
  int*   dsts  = (int*)take((size_t)E * 4);
  int*   col   = (int*)take((size_t)E * 4);
  float* QS    = (float*)take((size_t)NN * QSC * 4);                  // 30.7 MB
  unsigned short* KVH = (unsigned short*)take((size_t)NN * 256 * 2);  // 20.5 MB
  float* Hbuf  = (float*)take((size_t)NN * CHN * 4);
  (void)ws_size; (void)n_in; (void)out_size;

  // weight packing + edge decode + CSR build (same edge list for both layers)
  hipMemsetAsync(deg, 0, (size_t)NN * 4, stream);
  pack_all<<<(86912 + 255) / 256, 256, 0, stream>>>(
      Wq1, bq1, Wk1, bk1, Wv1, bv1, Ws1, bs1,
      Wq2, bq2, Wk2, bk2, Wv2, bv2, Ws2, bs2,
      Bh1, Bl1, Bh2, Bl2, bias1, bias2);
  detect_k<<<1, 64, 0, stream>>>(ei_raw, flag);
  decode_k<<<(E + 255) / 256, 256, 0, stream>>>(ei_raw, flag, srcs, dsts, deg, E);
  bsum_k<<<NBLK, SCAN_BLK, 0, stream>>>(deg, bsum);
  bscan_k<<<1, SCAN_BLK, 0, stream>>>(bsum, boff);
  rpwrite_k<<<NBLK, SCAN_BLK, 0, stream>>>(deg, boff, rp, cur);
  scatter_k<<<(E + 255) / 256, 256, 0, stream>>>(srcs, dsts, cur, col, E);

  // layer 1: x[40000x128] -> QS/KVH -> fused agg -> Hbuf (leaky relu)
  gemm_mfma<128><<<dim3(7, NN / 64), 256, 0, stream>>>(x, Bh1, Bl1, bias1, QS, KVH);
  agg_fused<<<NN, 128, 0, stream>>>(QS, KVH, rp, col, Hbuf, 1);

  // layer 2: Hbuf[40000x64] -> QS/KVH -> fused agg -> out (no activation)
  gemm_mfma<64><<<dim3(7, NN / 64), 256, 0, stream>>>(Hbuf, Bh2, Bl2, bias2, QS, KVH);
  agg_fused<<<NN, 128, 0, stream>>>(QS, KVH, rp, col, out, 0);
}